// Round 6
// baseline (195.701 us; speedup 1.0000x reference)
//
#include <hip/hip_runtime.h>
#include <math.h>

#define T_SEQ 2048
#define E 768
#define WIN 1024
#define KDIM 768
#define HS_SZ ((size_t)4096 * 768)
#define SCALE 0.21650635094610965f

typedef _Float16 f16x8 __attribute__((ext_vector_type(8)));
typedef _Float16 f16x4 __attribute__((ext_vector_type(4)));
typedef float f32x4 __attribute__((ext_vector_type(4)));

#define MFMA16(a, b, c) __builtin_amdgcn_mfma_f32_16x16x32_f16(a, b, c, 0, 0, 0)

// ---------------- prep: hi/lo splits + rotary table ----------------
__device__ inline void split4(const float* __restrict__ src, _Float16* __restrict__ dst,
                              size_t n, int i) {
    float4 x = *(const float4*)&src[i];
    f16x4 h, l;
    float xv[4] = {x.x, x.y, x.z, x.w};
    #pragma unroll
    for (int j = 0; j < 4; ++j) {
        _Float16 hh = (_Float16)xv[j];
        h[j] = hh;
        l[j] = (_Float16)(xv[j] - (float)hh);
    }
    *(f16x4*)&dst[i] = h;
    *(f16x4*)&dst[n + i] = l;
}

__global__ __launch_bounds__(256) void prep(
    const float* __restrict__ hs,
    const float* __restrict__ Wq, const float* __restrict__ Wk,
    const float* __restrict__ Wv, const float* __restrict__ Wo,
    _Float16* __restrict__ hs2,
    _Float16* __restrict__ Wq2, _Float16* __restrict__ Wk2,
    _Float16* __restrict__ Wv2, _Float16* __restrict__ Wo2,
    float2* __restrict__ rtab) {
    int tid = blockIdx.x * 256 + threadIdx.x;
    int i = tid * 4;
    if (i < 768 * 768) { split4(Wq, Wq2, 768 * 768, i); split4(Wo, Wo2, 768 * 768, i); }
    if (i < 192 * 768) { split4(Wk, Wk2, 192 * 768, i); split4(Wv, Wv2, 192 * 768, i); }
    split4(hs, hs2, HS_SZ, i);
    if (tid < 2048 * 32) {
        int t = tid >> 5, d = tid & 31;
        float inv = powf(10000.0f, -(float)(2 * d) * (1.0f / 64.0f));
        float s, c;
        sincosf((float)t * inv, &s, &c);
        rtab[tid] = make_float2(c, s);
    }
}

// ---------------- QKV GEMM: 128x128 tile, 64x64 wave, reg-prefetch pipeline ----
// Columns 0..767 = Q (12 heads), 768..959 = K (3 kv-heads), 960..1151 = V.
__global__ __launch_bounds__(256) void gemm_qkv(
    const _Float16* __restrict__ A2,
    const _Float16* __restrict__ Wq2, const _Float16* __restrict__ Wk2,
    const _Float16* __restrict__ Wv2, const float2* __restrict__ rtab,
    _Float16* __restrict__ q16, _Float16* __restrict__ k16,
    _Float16* __restrict__ vT16) {
    __shared__ __align__(16) _Float16 As[2][128][40];
    __shared__ __align__(16) _Float16 Bs[2][128][40];
    const int tid = threadIdx.x;
    const int n0 = blockIdx.x * 128;
    const int m0 = blockIdx.y * 128;
    const int w = tid >> 6, lane = tid & 63;
    const int mm = lane & 15, quad = lane >> 4;
    const int wm = (w & 1) * 64, wn = (w >> 1) * 64;
    const int srow = tid >> 1, shalf = (tid & 1) * 16;

    const _Float16* apH = &A2[(size_t)(m0 + srow) * KDIM + shalf];
    const _Float16* apL = apH + HS_SZ;
    int c = n0 + srow;
    const _Float16* bbase; size_t pstr; int br;
    if (c < 768)      { bbase = Wq2; pstr = (size_t)768 * 768; br = c; }
    else if (c < 960) { bbase = Wk2; pstr = (size_t)192 * 768; br = c - 768; }
    else              { bbase = Wv2; pstr = (size_t)192 * 768; br = c - 960; }
    const _Float16* bpH = &bbase[(size_t)br * KDIM + shalf];
    const _Float16* bpL = bpH + pstr;

    f32x4 acc[4][4] = {};
    f16x8 pf[8];

    pf[0] = *(const f16x8*)&apH[0]; pf[1] = *(const f16x8*)&apH[8];
    pf[2] = *(const f16x8*)&apL[0]; pf[3] = *(const f16x8*)&apL[8];
    pf[4] = *(const f16x8*)&bpH[0]; pf[5] = *(const f16x8*)&bpH[8];
    pf[6] = *(const f16x8*)&bpL[0]; pf[7] = *(const f16x8*)&bpL[8];
    *(f16x8*)&As[0][srow][shalf]     = pf[0];
    *(f16x8*)&As[0][srow][shalf + 8] = pf[1];
    *(f16x8*)&As[1][srow][shalf]     = pf[2];
    *(f16x8*)&As[1][srow][shalf + 8] = pf[3];
    *(f16x8*)&Bs[0][srow][shalf]     = pf[4];
    *(f16x8*)&Bs[0][srow][shalf + 8] = pf[5];
    *(f16x8*)&Bs[1][srow][shalf]     = pf[6];
    *(f16x8*)&Bs[1][srow][shalf + 8] = pf[7];
    __syncthreads();

    for (int k0 = 0; k0 < KDIM; k0 += 32) {
        const bool more = (k0 + 32 < KDIM);
        if (more) {
            int kn = k0 + 32;
            pf[0] = *(const f16x8*)&apH[kn]; pf[1] = *(const f16x8*)&apH[kn + 8];
            pf[2] = *(const f16x8*)&apL[kn]; pf[3] = *(const f16x8*)&apL[kn + 8];
            pf[4] = *(const f16x8*)&bpH[kn]; pf[5] = *(const f16x8*)&bpH[kn + 8];
            pf[6] = *(const f16x8*)&bpL[kn]; pf[7] = *(const f16x8*)&bpL[kn + 8];
        }
        f16x8 ah[4], al[4];
        #pragma unroll
        for (int mt = 0; mt < 4; ++mt) {
            ah[mt] = *(const f16x8*)&As[0][wm + mt * 16 + mm][quad * 8];
            al[mt] = *(const f16x8*)&As[1][wm + mt * 16 + mm][quad * 8];
        }
        #pragma unroll
        for (int nt = 0; nt < 4; ++nt) {
            f16x8 bh = *(const f16x8*)&Bs[0][wn + nt * 16 + mm][quad * 8];
            f16x8 bl = *(const f16x8*)&Bs[1][wn + nt * 16 + mm][quad * 8];
            #pragma unroll
            for (int mt = 0; mt < 4; ++mt) {
                acc[mt][nt] = MFMA16(al[mt], bh, acc[mt][nt]);
                acc[mt][nt] = MFMA16(ah[mt], bl, acc[mt][nt]);
                acc[mt][nt] = MFMA16(ah[mt], bh, acc[mt][nt]);
            }
        }
        if (more) {
            __syncthreads();
            *(f16x8*)&As[0][srow][shalf]     = pf[0];
            *(f16x8*)&As[0][srow][shalf + 8] = pf[1];
            *(f16x8*)&As[1][srow][shalf]     = pf[2];
            *(f16x8*)&As[1][srow][shalf + 8] = pf[3];
            *(f16x8*)&Bs[0][srow][shalf]     = pf[4];
            *(f16x8*)&Bs[0][srow][shalf + 8] = pf[5];
            *(f16x8*)&Bs[1][srow][shalf]     = pf[6];
            *(f16x8*)&Bs[1][srow][shalf + 8] = pf[7];
            __syncthreads();
        }
    }

    // ---- fused epilogue (rotary + f16 emit), per wave col-base ----
    const int cbw = n0 + wn;
    #pragma unroll
    for (int mt = 0; mt < 4; ++mt) {
        #pragma unroll
        for (int r = 0; r < 4; ++r) {
            int row = m0 + wm + mt * 16 + quad * 4 + r;
            int t = row & (T_SEQ - 1);
            int b = row >> 11;
            if (cbw < 768) {
                int hq = cbw >> 6;
                _Float16* dst = &q16[(size_t)row * E + hq * 64 + mm];
                #pragma unroll
                for (int nt = 0; nt < 2; ++nt) {
                    int d = nt * 16 + mm;
                    float2 cs = rtab[t * 32 + d];
                    float x1 = acc[mt][nt][r], x2 = acc[mt][nt + 2][r];
                    dst[nt * 16]       = (_Float16)((x1 * cs.x - x2 * cs.y) * SCALE);
                    dst[(nt + 2) * 16] = (_Float16)((x1 * cs.y + x2 * cs.x) * SCALE);
                }
            } else if (cbw < 960) {
                int kvh = (cbw - 768) >> 6;
                _Float16* dst = &k16[(((size_t)(b * 3 + kvh)) * T_SEQ + t) * 64 + mm];
                #pragma unroll
                for (int nt = 0; nt < 2; ++nt) {
                    int d = nt * 16 + mm;
                    float2 cs = rtab[t * 32 + d];
                    float x1 = acc[mt][nt][r], x2 = acc[mt][nt + 2][r];
                    dst[nt * 16]       = (_Float16)(x1 * cs.x - x2 * cs.y);
                    dst[(nt + 2) * 16] = (_Float16)(x1 * cs.y + x2 * cs.x);
                }
            } else {
                int kvh = (cbw - 960) >> 6;
                #pragma unroll
                for (int nt = 0; nt < 4; ++nt) {
                    int d = nt * 16 + mm;
                    vT16[(((size_t)(b * 3 + kvh)) * 64 + d) * T_SEQ + t] = (_Float16)acc[mt][nt][r];
                }
            }
        }
    }
}

// ---------------- output-projection GEMM: same tile/pipeline, f32 out -------
__global__ __launch_bounds__(256) void gemm_out(
    const _Float16* __restrict__ A2, const _Float16* __restrict__ B2,
    float* __restrict__ C) {
    __shared__ __align__(16) _Float16 As[2][128][40];
    __shared__ __align__(16) _Float16 Bs[2][128][40];
    const int tid = threadIdx.x;
    const int n0 = blockIdx.x * 128;
    const int m0 = blockIdx.y * 128;
    const int w = tid >> 6, lane = tid & 63;
    const int mm = lane & 15, quad = lane >> 4;
    const int wm = (w & 1) * 64, wn = (w >> 1) * 64;
    const int srow = tid >> 1, shalf = (tid & 1) * 16;

    const _Float16* apH = &A2[(size_t)(m0 + srow) * KDIM + shalf];
    const _Float16* apL = apH + HS_SZ;
    const _Float16* bpH = &B2[(size_t)(n0 + srow) * KDIM + shalf];
    const _Float16* bpL = bpH + (size_t)768 * 768;

    f32x4 acc[4][4] = {};
    f16x8 pf[8];

    pf[0] = *(const f16x8*)&apH[0]; pf[1] = *(const f16x8*)&apH[8];
    pf[2] = *(const f16x8*)&apL[0]; pf[3] = *(const f16x8*)&apL[8];
    pf[4] = *(const f16x8*)&bpH[0]; pf[5] = *(const f16x8*)&bpH[8];
    pf[6] = *(const f16x8*)&bpL[0]; pf[7] = *(const f16x8*)&bpL[8];
    *(f16x8*)&As[0][srow][shalf]     = pf[0];
    *(f16x8*)&As[0][srow][shalf + 8] = pf[1];
    *(f16x8*)&As[1][srow][shalf]     = pf[2];
    *(f16x8*)&As[1][srow][shalf + 8] = pf[3];
    *(f16x8*)&Bs[0][srow][shalf]     = pf[4];
    *(f16x8*)&Bs[0][srow][shalf + 8] = pf[5];
    *(f16x8*)&Bs[1][srow][shalf]     = pf[6];
    *(f16x8*)&Bs[1][srow][shalf + 8] = pf[7];
    __syncthreads();

    for (int k0 = 0; k0 < KDIM; k0 += 32) {
        const bool more = (k0 + 32 < KDIM);
        if (more) {
            int kn = k0 + 32;
            pf[0] = *(const f16x8*)&apH[kn]; pf[1] = *(const f16x8*)&apH[kn + 8];
            pf[2] = *(const f16x8*)&apL[kn]; pf[3] = *(const f16x8*)&apL[kn + 8];
            pf[4] = *(const f16x8*)&bpH[kn]; pf[5] = *(const f16x8*)&bpH[kn + 8];
            pf[6] = *(const f16x8*)&bpL[kn]; pf[7] = *(const f16x8*)&bpL[kn + 8];
        }
        f16x8 ah[4], al[4];
        #pragma unroll
        for (int mt = 0; mt < 4; ++mt) {
            ah[mt] = *(const f16x8*)&As[0][wm + mt * 16 + mm][quad * 8];
            al[mt] = *(const f16x8*)&As[1][wm + mt * 16 + mm][quad * 8];
        }
        #pragma unroll
        for (int nt = 0; nt < 4; ++nt) {
            f16x8 bh = *(const f16x8*)&Bs[0][wn + nt * 16 + mm][quad * 8];
            f16x8 bl = *(const f16x8*)&Bs[1][wn + nt * 16 + mm][quad * 8];
            #pragma unroll
            for (int mt = 0; mt < 4; ++mt) {
                acc[mt][nt] = MFMA16(al[mt], bh, acc[mt][nt]);
                acc[mt][nt] = MFMA16(ah[mt], bl, acc[mt][nt]);
                acc[mt][nt] = MFMA16(ah[mt], bh, acc[mt][nt]);
            }
        }
        if (more) {
            __syncthreads();
            *(f16x8*)&As[0][srow][shalf]     = pf[0];
            *(f16x8*)&As[0][srow][shalf + 8] = pf[1];
            *(f16x8*)&As[1][srow][shalf]     = pf[2];
            *(f16x8*)&As[1][srow][shalf + 8] = pf[3];
            *(f16x8*)&Bs[0][srow][shalf]     = pf[4];
            *(f16x8*)&Bs[0][srow][shalf + 8] = pf[5];
            *(f16x8*)&Bs[1][srow][shalf]     = pf[6];
            *(f16x8*)&Bs[1][srow][shalf + 8] = pf[7];
            __syncthreads();
        }
    }
    #pragma unroll
    for (int mt = 0; mt < 4; ++mt)
        #pragma unroll
        for (int r = 0; r < 4; ++r) {
            int row = m0 + wm + mt * 16 + quad * 4 + r;
            float* cp = &C[(size_t)row * 768 + n0 + wn + mm];
            #pragma unroll
            for (int nt = 0; nt < 4; ++nt)
                cp[nt * 16] = acc[mt][nt][r];
        }
}

// ---------------- MFMA flash attention ----------------
__global__ __launch_bounds__(256) void attn_mfma(const _Float16* __restrict__ q16,
                                                 const _Float16* __restrict__ k16,
                                                 const _Float16* __restrict__ vT16,
                                                 _Float16* __restrict__ aout2) {
    __shared__ __align__(16) _Float16 k_s[64][72];
    __shared__ __align__(16) _Float16 vT_s[64][72];
    __shared__ __align__(16) _Float16 p_s[4][16][72];

    const int b = blockIdx.z, h = blockIdx.y;
    const int i0 = blockIdx.x * 64;
    const int kvh = h >> 2;
    const int plane = b * 3 + kvh;
    const int tid = threadIdx.x;
    const int w = tid >> 6, lane = tid & 63;
    const int m = lane & 15, quad = lane >> 4;

    int s0 = i0 - 512;      s0 = s0 < 0 ? 0 : (s0 > 1024 ? 1024 : s0);
    int sL = i0 + 63 - 512; sL = sL < 0 ? 0 : (sL > 1024 ? 1024 : sL);
    const int nc = (sL + WIN - s0 + 63) >> 6;

    const int qi = i0 + w * 16 + m;
    int start_q = qi - 512; start_q = start_q < 0 ? 0 : (start_q > 1024 ? 1024 : start_q);

    f16x8 qf[2];
    {
        const _Float16* qp = &q16[((size_t)(b * T_SEQ + qi)) * E + h * 64 + quad * 8];
        qf[0] = *(const f16x8*)&qp[0];
        qf[1] = *(const f16x8*)&qp[32];
    }

    f32x4 o[4] = {};
    float l_run = 0.0f;

    const int skey = tid >> 2, sseg = (tid & 3) * 16;

    for (int ci = 0; ci < nc; ++ci) {
        const int c0 = s0 + ci * 64;
        __syncthreads();
        {
            const _Float16* kp = &k16[((size_t)plane * T_SEQ + c0 + skey) * 64 + sseg];
            *(f16x8*)&k_s[skey][sseg]     = *(const f16x8*)&kp[0];
            *(f16x8*)&k_s[skey][sseg + 8] = *(const f16x8*)&kp[8];
        }
        {
            const _Float16* vp = &vT16[((size_t)plane * 64 + skey) * T_SEQ + c0 + sseg];
            *(f16x8*)&vT_s[skey][sseg]     = *(const f16x8*)&vp[0];
            *(f16x8*)&vT_s[skey][sseg + 8] = *(const f16x8*)&vp[8];
        }
        __syncthreads();

        f32x4 st[4] = {};
        #pragma unroll
        for (int t = 0; t < 4; ++t) {
            #pragma unroll
            for (int s = 0; s < 2; ++s) {
                f16x8 a = *(const f16x8*)&k_s[t * 16 + m][s * 32 + quad * 8];
                st[t] = MFMA16(a, qf[s], st[t]);
            }
        }

        const bool boundary = (c0 < sL) || (c0 + 63 > s0 + 1023);
        if (boundary) {
            #pragma unroll
            for (int t = 0; t < 4; ++t)
                #pragma unroll
                for (int r = 0; r < 4; ++r) {
                    int j = c0 + t * 16 + quad * 4 + r;
                    bool valid = (j >= start_q) && (j < start_q + WIN);
                    st[t][r] = valid ? st[t][r] : -INFINITY;
                }
        }

        #pragma unroll
        for (int t = 0; t < 4; ++t) {
            float p0 = __expf(st[t][0]);
            float p1 = __expf(st[t][1]);
            float p2 = __expf(st[t][2]);
            float p3 = __expf(st[t][3]);
            l_run += (p0 + p1) + (p2 + p3);
            f16x4 pv = {(_Float16)p0, (_Float16)p1, (_Float16)p2, (_Float16)p3};
            *(f16x4*)&p_s[w][m][t * 16 + quad * 4] = pv;
        }

        f16x8 bp0 = *(const f16x8*)&p_s[w][m][quad * 8];
        f16x8 bp1 = *(const f16x8*)&p_s[w][m][32 + quad * 8];
        #pragma unroll
        for (int mt = 0; mt < 4; ++mt) {
            f16x8 a0 = *(const f16x8*)&vT_s[mt * 16 + m][quad * 8];
            f16x8 a1 = *(const f16x8*)&vT_s[mt * 16 + m][32 + quad * 8];
            o[mt] = MFMA16(a0, bp0, o[mt]);
            o[mt] = MFMA16(a1, bp1, o[mt]);
        }
    }

    float l_tot = l_run;
    l_tot += __shfl_xor(l_tot, 16);
    l_tot += __shfl_xor(l_tot, 32);
    float rl = 1.0f / l_tot;
    _Float16* opH = &aout2[((size_t)(b * T_SEQ + qi)) * E + h * 64];
    _Float16* opL = opH + HS_SZ;
    #pragma unroll
    for (int mt = 0; mt < 4; ++mt)
        #pragma unroll
        for (int r = 0; r < 4; ++r) {
            float x = o[mt][r] * rl;
            _Float16 hh = (_Float16)x;
            opH[mt * 16 + quad * 4 + r] = hh;
            opL[mt * 16 + quad * 4 + r] = (_Float16)(x - (float)hh);
        }
}

extern "C" void kernel_launch(void* const* d_in, const int* in_sizes, int n_in,
                              void* d_out, int out_size, void* d_ws, size_t ws_size,
                              hipStream_t stream) {
    const float* hs = (const float*)d_in[0];
    const float* Wq = (const float*)d_in[1];
    const float* Wk = (const float*)d_in[2];
    const float* Wv = (const float*)d_in[3];
    const float* Wo = (const float*)d_in[4];
    float* out = (float*)d_out;

    _Float16* hs2   = (_Float16*)d_ws;            // 2 * 4096*768 f16
    _Float16* aout2 = hs2 + 2 * HS_SZ;            // 2 * 4096*768 f16
    _Float16* q16   = aout2 + 2 * HS_SZ;          // 4096*768 f16
    _Float16* k16   = q16 + HS_SZ;                // 6*2048*64
    _Float16* vT16  = k16 + 6 * 2048 * 64;        // 6*64*2048
    _Float16* Wq2   = vT16 + 6 * 64 * 2048;       // 2*768*768
    _Float16* Wk2   = Wq2 + 2 * 768 * 768;        // 2*192*768
    _Float16* Wv2   = Wk2 + 2 * 192 * 768;
    _Float16* Wo2   = Wv2 + 2 * 192 * 768;        // 2*768*768
    float2*   rtab  = (float2*)(Wo2 + 2 * 768 * 768); // 2048*32 float2

    dim3 blk(256);
    prep<<<dim3((int)(HS_SZ / 4 / 256)), blk, 0, stream>>>(hs, Wq, Wk, Wv, Wo,
                                                           hs2, Wq2, Wk2, Wv2, Wo2, rtab);
    gemm_qkv<<<dim3(9, 32), blk, 0, stream>>>(hs2, Wq2, Wk2, Wv2, rtab, q16, k16, vT16);
    attn_mfma<<<dim3(32, 12, 2), blk, 0, stream>>>(q16, k16, vT16, aout2);
    gemm_out<<<dim3(6, 32), blk, 0, stream>>>(aout2, Wo2, out);
}

// Round 7
// 163.987 us; speedup vs baseline: 1.1934x; 1.1934x over previous
//
#include <hip/hip_runtime.h>
#include <math.h>

#define T_SEQ 2048
#define E 768
#define WIN 1024
#define KDIM 768
#define HS_SZ ((size_t)4096 * 768)
#define SCALE 0.21650635094610965f

typedef _Float16 f16x8 __attribute__((ext_vector_type(8)));
typedef _Float16 f16x4 __attribute__((ext_vector_type(4)));
typedef float f32x4 __attribute__((ext_vector_type(4)));
typedef __attribute__((address_space(3))) _Float16 lf16;

#define MFMA16(a, b, c) __builtin_amdgcn_mfma_f32_16x16x32_f16(a, b, c, 0, 0, 0)

__device__ __forceinline__ void dma16(const _Float16* g, lf16* l) {
    __builtin_amdgcn_global_load_lds(
        (const __attribute__((address_space(1))) void*)g,
        (__attribute__((address_space(3))) void*)l, 16, 0, 0);
}

// ---------------- prep: hi/lo splits + rotary table ----------------
__device__ inline void split4(const float* __restrict__ src, _Float16* __restrict__ dst,
                              size_t n, int i) {
    float4 x = *(const float4*)&src[i];
    f16x4 h, l;
    float xv[4] = {x.x, x.y, x.z, x.w};
    #pragma unroll
    for (int j = 0; j < 4; ++j) {
        _Float16 hh = (_Float16)xv[j];
        h[j] = hh;
        l[j] = (_Float16)(xv[j] - (float)hh);
    }
    *(f16x4*)&dst[i] = h;
    *(f16x4*)&dst[n + i] = l;
}

__global__ __launch_bounds__(256) void prep(
    const float* __restrict__ hs,
    const float* __restrict__ Wq, const float* __restrict__ Wk,
    const float* __restrict__ Wv, const float* __restrict__ Wo,
    _Float16* __restrict__ hs2,
    _Float16* __restrict__ Wq2, _Float16* __restrict__ Wk2,
    _Float16* __restrict__ Wv2, _Float16* __restrict__ Wo2,
    float2* __restrict__ rtab) {
    int tid = blockIdx.x * 256 + threadIdx.x;
    int i = tid * 4;
    if (i < 768 * 768) { split4(Wq, Wq2, 768 * 768, i); split4(Wo, Wo2, 768 * 768, i); }
    if (i < 192 * 768) { split4(Wk, Wk2, 192 * 768, i); split4(Wv, Wv2, 192 * 768, i); }
    split4(hs, hs2, HS_SZ, i);
    if (tid < 2048 * 32) {
        int t = tid >> 5, d = tid & 31;
        float inv = powf(10000.0f, -(float)(2 * d) * (1.0f / 64.0f));
        float s, c;
        sincosf((float)t * inv, &s, &c);
        rtab[tid] = make_float2(c, s);
    }
}

// ---------------- QKV GEMM: 128x64 tile, BK=64, global_load_lds + XOR swizzle
// LDS layout: [pl][row][granule'] with granule' = granule ^ (row&7), no pad.
// bx 0..11 -> Q head bx; 12..14 -> K kv-head; 15..17 -> V kv-head.
__global__ __launch_bounds__(256) void gemm_qkv(
    const _Float16* __restrict__ A2,
    const _Float16* __restrict__ Wq2, const _Float16* __restrict__ Wk2,
    const _Float16* __restrict__ Wv2, const float2* __restrict__ rtab,
    _Float16* __restrict__ q16, _Float16* __restrict__ k16,
    _Float16* __restrict__ vT16) {
    __shared__ __align__(16) _Float16 As[2 * 128 * 64];   // 32 KB
    __shared__ __align__(16) _Float16 Bs[2 * 64 * 64];    // 16 KB
    const int tid = threadIdx.x;
    const int bx = blockIdx.x;
    const int m0 = blockIdx.y * 128;
    const int w = tid >> 6, lane = tid & 63;
    const int mm = lane & 15, quad = lane >> 4;

    const _Float16* bbase; size_t pstr; int brb;
    if (bx < 12)      { bbase = Wq2; pstr = (size_t)768 * 768; brb = bx * 64; }
    else if (bx < 15) { bbase = Wk2; pstr = (size_t)192 * 768; brb = (bx - 12) * 64; }
    else              { bbase = Wv2; pstr = (size_t)192 * 768; brb = (bx - 15) * 64; }

    // Per-lane DMA source decoding: chunk = 8 rows x 128B; lane i covers
    // row += i>>3, LDS granule i&7 which holds logical granule (i&7)^(i>>3).
    const int rofs = lane >> 3;
    const int gsw = ((lane & 7) ^ rofs) * 8;

    const _Float16* agp[8]; lf16* alp[8];
    #pragma unroll
    for (int j = 0; j < 8; ++j) {
        int c = j * 4 + w;
        int pl = c >> 4, rr = (c & 15) * 8 + rofs;
        agp[j] = A2 + (size_t)pl * HS_SZ + (size_t)(m0 + rr) * KDIM + gsw;
        alp[j] = ((lf16*)As) + c * 512;
    }
    const _Float16* bgp[4]; lf16* blp[4];
    #pragma unroll
    for (int j = 0; j < 4; ++j) {
        int c = j * 4 + w;
        int pl = c >> 3, rr = (c & 7) * 8 + rofs;
        bgp[j] = bbase + (size_t)pl * pstr + (size_t)(brb + rr) * KDIM + gsw;
        blp[j] = ((lf16*)Bs) + c * 512;
    }

    f32x4 acc[2][4] = {};
    const int xr = mm & 7;

    for (int it = 0; it < 12; ++it) {
        const int ke = it * 64;
        __syncthreads();
        #pragma unroll
        for (int j = 0; j < 8; ++j) dma16(agp[j] + ke, alp[j]);
        #pragma unroll
        for (int j = 0; j < 4; ++j) dma16(bgp[j] + ke, blp[j]);
        __syncthreads();
        #pragma unroll
        for (int s = 0; s < 2; ++s) {
            const int gq = ((s * 4 + quad) ^ xr) * 8;
            f16x8 ah[2], alo[2];
            #pragma unroll
            for (int mt = 0; mt < 2; ++mt) {
                int rbase = (w * 32 + mt * 16 + mm) * 64 + gq;
                ah[mt]  = *(const f16x8*)&As[rbase];
                alo[mt] = *(const f16x8*)&As[8192 + rbase];
            }
            #pragma unroll
            for (int nt = 0; nt < 4; ++nt) {
                int rb = (nt * 16 + mm) * 64 + gq;
                f16x8 bh = *(const f16x8*)&Bs[rb];
                f16x8 bl = *(const f16x8*)&Bs[4096 + rb];
                #pragma unroll
                for (int mt = 0; mt < 2; ++mt) {
                    acc[mt][nt] = MFMA16(alo[mt], bh, acc[mt][nt]);
                    acc[mt][nt] = MFMA16(ah[mt], bl, acc[mt][nt]);
                    acc[mt][nt] = MFMA16(ah[mt], bh, acc[mt][nt]);
                }
            }
        }
    }

    // ---- fused epilogue (rotary + f16 emit) ----
    #pragma unroll
    for (int mt = 0; mt < 2; ++mt) {
        #pragma unroll
        for (int r = 0; r < 4; ++r) {
            int row = m0 + w * 32 + mt * 16 + quad * 4 + r;
            int t = row & (T_SEQ - 1);
            int b = row >> 11;
            if (bx < 12) {
                _Float16* dst = &q16[(size_t)row * E + bx * 64 + mm];
                #pragma unroll
                for (int nt = 0; nt < 2; ++nt) {
                    int d = nt * 16 + mm;
                    float2 cs = rtab[t * 32 + d];
                    float x1 = acc[mt][nt][r], x2 = acc[mt][nt + 2][r];
                    dst[nt * 16]       = (_Float16)((x1 * cs.x - x2 * cs.y) * SCALE);
                    dst[(nt + 2) * 16] = (_Float16)((x1 * cs.y + x2 * cs.x) * SCALE);
                }
            } else if (bx < 15) {
                int kvh = bx - 12;
                _Float16* dst = &k16[(((size_t)(b * 3 + kvh)) * T_SEQ + t) * 64 + mm];
                #pragma unroll
                for (int nt = 0; nt < 2; ++nt) {
                    int d = nt * 16 + mm;
                    float2 cs = rtab[t * 32 + d];
                    float x1 = acc[mt][nt][r], x2 = acc[mt][nt + 2][r];
                    dst[nt * 16]       = (_Float16)(x1 * cs.x - x2 * cs.y);
                    dst[(nt + 2) * 16] = (_Float16)(x1 * cs.y + x2 * cs.x);
                }
            } else {
                int kvh = bx - 15;
                #pragma unroll
                for (int nt = 0; nt < 4; ++nt) {
                    int d = nt * 16 + mm;
                    vT16[(((size_t)(b * 3 + kvh)) * 64 + d) * T_SEQ + t] = (_Float16)acc[mt][nt][r];
                }
            }
        }
    }
}

// ---------------- output-projection GEMM: same structure, f32 out ----------
__global__ __launch_bounds__(256) void gemm_out(
    const _Float16* __restrict__ A2, const _Float16* __restrict__ B2,
    float* __restrict__ C) {
    __shared__ __align__(16) _Float16 As[2 * 128 * 64];
    __shared__ __align__(16) _Float16 Bs[2 * 64 * 64];
    const int tid = threadIdx.x;
    const int n0 = blockIdx.x * 64;
    const int m0 = blockIdx.y * 128;
    const int w = tid >> 6, lane = tid & 63;
    const int mm = lane & 15, quad = lane >> 4;

    const int rofs = lane >> 3;
    const int gsw = ((lane & 7) ^ rofs) * 8;

    const _Float16* agp[8]; lf16* alp[8];
    #pragma unroll
    for (int j = 0; j < 8; ++j) {
        int c = j * 4 + w;
        int pl = c >> 4, rr = (c & 15) * 8 + rofs;
        agp[j] = A2 + (size_t)pl * HS_SZ + (size_t)(m0 + rr) * KDIM + gsw;
        alp[j] = ((lf16*)As) + c * 512;
    }
    const _Float16* bgp[4]; lf16* blp[4];
    #pragma unroll
    for (int j = 0; j < 4; ++j) {
        int c = j * 4 + w;
        int pl = c >> 3, rr = (c & 7) * 8 + rofs;
        bgp[j] = B2 + (size_t)pl * ((size_t)768 * 768) + (size_t)(n0 + rr) * KDIM + gsw;
        blp[j] = ((lf16*)Bs) + c * 512;
    }

    f32x4 acc[2][4] = {};
    const int xr = mm & 7;

    for (int it = 0; it < 12; ++it) {
        const int ke = it * 64;
        __syncthreads();
        #pragma unroll
        for (int j = 0; j < 8; ++j) dma16(agp[j] + ke, alp[j]);
        #pragma unroll
        for (int j = 0; j < 4; ++j) dma16(bgp[j] + ke, blp[j]);
        __syncthreads();
        #pragma unroll
        for (int s = 0; s < 2; ++s) {
            const int gq = ((s * 4 + quad) ^ xr) * 8;
            f16x8 ah[2], alo[2];
            #pragma unroll
            for (int mt = 0; mt < 2; ++mt) {
                int rbase = (w * 32 + mt * 16 + mm) * 64 + gq;
                ah[mt]  = *(const f16x8*)&As[rbase];
                alo[mt] = *(const f16x8*)&As[8192 + rbase];
            }
            #pragma unroll
            for (int nt = 0; nt < 4; ++nt) {
                int rb = (nt * 16 + mm) * 64 + gq;
                f16x8 bh = *(const f16x8*)&Bs[rb];
                f16x8 bl = *(const f16x8*)&Bs[4096 + rb];
                #pragma unroll
                for (int mt = 0; mt < 2; ++mt) {
                    acc[mt][nt] = MFMA16(alo[mt], bh, acc[mt][nt]);
                    acc[mt][nt] = MFMA16(ah[mt], bl, acc[mt][nt]);
                    acc[mt][nt] = MFMA16(ah[mt], bh, acc[mt][nt]);
                }
            }
        }
    }
    #pragma unroll
    for (int mt = 0; mt < 2; ++mt)
        #pragma unroll
        for (int r = 0; r < 4; ++r) {
            int row = m0 + w * 32 + mt * 16 + quad * 4 + r;
            float* cp = &C[(size_t)row * 768 + n0 + mm];
            #pragma unroll
            for (int nt = 0; nt < 4; ++nt)
                cp[nt * 16] = acc[mt][nt][r];
        }
}

// ---------------- MFMA flash attention ----------------
__global__ __launch_bounds__(256) void attn_mfma(const _Float16* __restrict__ q16,
                                                 const _Float16* __restrict__ k16,
                                                 const _Float16* __restrict__ vT16,
                                                 _Float16* __restrict__ aout2) {
    __shared__ __align__(16) _Float16 k_s[64][72];
    __shared__ __align__(16) _Float16 vT_s[64][72];
    __shared__ __align__(16) _Float16 p_s[4][16][72];

    const int b = blockIdx.z, h = blockIdx.y;
    const int i0 = blockIdx.x * 64;
    const int kvh = h >> 2;
    const int plane = b * 3 + kvh;
    const int tid = threadIdx.x;
    const int w = tid >> 6, lane = tid & 63;
    const int m = lane & 15, quad = lane >> 4;

    int s0 = i0 - 512;      s0 = s0 < 0 ? 0 : (s0 > 1024 ? 1024 : s0);
    int sL = i0 + 63 - 512; sL = sL < 0 ? 0 : (sL > 1024 ? 1024 : sL);
    const int nc = (sL + WIN - s0 + 63) >> 6;

    const int qi = i0 + w * 16 + m;
    int start_q = qi - 512; start_q = start_q < 0 ? 0 : (start_q > 1024 ? 1024 : start_q);

    f16x8 qf[2];
    {
        const _Float16* qp = &q16[((size_t)(b * T_SEQ + qi)) * E + h * 64 + quad * 8];
        qf[0] = *(const f16x8*)&qp[0];
        qf[1] = *(const f16x8*)&qp[32];
    }

    f32x4 o[4] = {};
    float l_run = 0.0f;

    const int skey = tid >> 2, sseg = (tid & 3) * 16;

    for (int ci = 0; ci < nc; ++ci) {
        const int c0 = s0 + ci * 64;
        __syncthreads();
        {
            const _Float16* kp = &k16[((size_t)plane * T_SEQ + c0 + skey) * 64 + sseg];
            *(f16x8*)&k_s[skey][sseg]     = *(const f16x8*)&kp[0];
            *(f16x8*)&k_s[skey][sseg + 8] = *(const f16x8*)&kp[8];
        }
        {
            const _Float16* vp = &vT16[((size_t)plane * 64 + skey) * T_SEQ + c0 + sseg];
            *(f16x8*)&vT_s[skey][sseg]     = *(const f16x8*)&vp[0];
            *(f16x8*)&vT_s[skey][sseg + 8] = *(const f16x8*)&vp[8];
        }
        __syncthreads();

        f32x4 st[4] = {};
        #pragma unroll
        for (int t = 0; t < 4; ++t) {
            #pragma unroll
            for (int s = 0; s < 2; ++s) {
                f16x8 a = *(const f16x8*)&k_s[t * 16 + m][s * 32 + quad * 8];
                st[t] = MFMA16(a, qf[s], st[t]);
            }
        }

        const bool boundary = (c0 < sL) || (c0 + 63 > s0 + 1023);
        if (boundary) {
            #pragma unroll
            for (int t = 0; t < 4; ++t)
                #pragma unroll
                for (int r = 0; r < 4; ++r) {
                    int j = c0 + t * 16 + quad * 4 + r;
                    bool valid = (j >= start_q) && (j < start_q + WIN);
                    st[t][r] = valid ? st[t][r] : -INFINITY;
                }
        }

        #pragma unroll
        for (int t = 0; t < 4; ++t) {
            float p0 = __expf(st[t][0]);
            float p1 = __expf(st[t][1]);
            float p2 = __expf(st[t][2]);
            float p3 = __expf(st[t][3]);
            l_run += (p0 + p1) + (p2 + p3);
            f16x4 pv = {(_Float16)p0, (_Float16)p1, (_Float16)p2, (_Float16)p3};
            *(f16x4*)&p_s[w][m][t * 16 + quad * 4] = pv;
        }

        f16x8 bp0 = *(const f16x8*)&p_s[w][m][quad * 8];
        f16x8 bp1 = *(const f16x8*)&p_s[w][m][32 + quad * 8];
        #pragma unroll
        for (int mt = 0; mt < 4; ++mt) {
            f16x8 a0 = *(const f16x8*)&vT_s[mt * 16 + m][quad * 8];
            f16x8 a1 = *(const f16x8*)&vT_s[mt * 16 + m][32 + quad * 8];
            o[mt] = MFMA16(a0, bp0, o[mt]);
            o[mt] = MFMA16(a1, bp1, o[mt]);
        }
    }

    float l_tot = l_run;
    l_tot += __shfl_xor(l_tot, 16);
    l_tot += __shfl_xor(l_tot, 32);
    float rl = 1.0f / l_tot;
    _Float16* opH = &aout2[((size_t)(b * T_SEQ + qi)) * E + h * 64];
    _Float16* opL = opH + HS_SZ;
    #pragma unroll
    for (int mt = 0; mt < 4; ++mt)
        #pragma unroll
        for (int r = 0; r < 4; ++r) {
            float x = o[mt][r] * rl;
            _Float16 hh = (_Float16)x;
            opH[mt * 16 + quad * 4 + r] = hh;
            opL[mt * 16 + quad * 4 + r] = (_Float16)(x - (float)hh);
        }
}

extern "C" void kernel_launch(void* const* d_in, const int* in_sizes, int n_in,
                              void* d_out, int out_size, void* d_ws, size_t ws_size,
                              hipStream_t stream) {
    const float* hs = (const float*)d_in[0];
    const float* Wq = (const float*)d_in[1];
    const float* Wk = (const float*)d_in[2];
    const float* Wv = (const float*)d_in[3];
    const float* Wo = (const float*)d_in[4];
    float* out = (float*)d_out;

    _Float16* hs2   = (_Float16*)d_ws;            // 2 * 4096*768 f16
    _Float16* aout2 = hs2 + 2 * HS_SZ;            // 2 * 4096*768 f16
    _Float16* q16   = aout2 + 2 * HS_SZ;          // 4096*768 f16
    _Float16* k16   = q16 + HS_SZ;                // 6*2048*64
    _Float16* vT16  = k16 + 6 * 2048 * 64;        // 6*64*2048
    _Float16* Wq2   = vT16 + 6 * 64 * 2048;       // 2*768*768
    _Float16* Wk2   = Wq2 + 2 * 768 * 768;        // 2*192*768
    _Float16* Wv2   = Wk2 + 2 * 192 * 768;
    _Float16* Wo2   = Wv2 + 2 * 192 * 768;        // 2*768*768
    float2*   rtab  = (float2*)(Wo2 + 2 * 768 * 768); // 2048*32 float2

    dim3 blk(256);
    prep<<<dim3((int)(HS_SZ / 4 / 256)), blk, 0, stream>>>(hs, Wq, Wk, Wv, Wo,
                                                           hs2, Wq2, Wk2, Wv2, Wo2, rtab);
    gemm_qkv<<<dim3(18, 32), blk, 0, stream>>>(hs2, Wq2, Wk2, Wv2, rtab, q16, k16, vT16);
    attn_mfma<<<dim3(32, 12, 2), blk, 0, stream>>>(q16, k16, vT16, aout2);
    gemm_out<<<dim3(12, 32), blk, 0, stream>>>(aout2, Wo2, out);
}